// Round 1
// baseline (136.665 us; speedup 1.0000x reference)
//
#include <hip/hip_runtime.h>
#include <math.h>

#if defined(__has_builtin)
#  if __has_builtin(__builtin_amdgcn_exp2f)
#    define EXP2F(x) __builtin_amdgcn_exp2f(x)
#  else
#    define EXP2F(x) exp2f(x)
#  endif
#else
#  define EXP2F(x) exp2f(x)
#endif

constexpr int   DD  = 16;                      // feature dim
constexpr int   SW  = 4;                       // samples per wave
constexpr float T2  = 72.13475204444817f;      // 50 / ln(2): exp(50*x) = exp2(T2*x)
constexpr float THR = 60.0f;                   // guard threshold in exp2 units

__device__ __forceinline__ float wave_max64(float v) {
#pragma unroll
    for (int m = 32; m >= 1; m >>= 1) v = fmaxf(v, __shfl_xor(v, m, 64));
    return v;
}
__device__ __forceinline__ float wave_sum64(float v) {
#pragma unroll
    for (int m = 32; m >= 1; m >>= 1) v += __shfl_xor(v, m, 64);
    return v;
}
// force a wave-uniform float into an SGPR
__device__ __forceinline__ float uni(float v) {
    return __int_as_float(__builtin_amdgcn_readfirstlane(__float_as_int(v)));
}

__global__ __launch_bounds__(64, 3)
void finite_fwd(const float* __restrict__ X, const float* __restrict__ Y,
                const float* __restrict__ B, float* __restrict__ out,
                int N, int C)
{
    const int lane  = threadIdx.x & 63;
    const int nbase = blockIdx.x * SW;

    // X rows for this wave's 4 samples — wave-uniform -> SGPRs
    float xs[SW][DD];
#pragma unroll
    for (int i = 0; i < SW; ++i) {
        const float* xp = X + (size_t)(nbase + i) * DD;
#pragma unroll
        for (int k = 0; k < DD; ++k) xs[i][k] = uni(xp[k]);
    }

    // online-softmax state per sample (per-lane partials over this lane's candidates)
    float m2[SW], l[SW], fx[SW], ch[SW][DD];
#pragma unroll
    for (int i = 0; i < SW; ++i) {
        m2[i] = -INFINITY; l[i] = 0.f; fx[i] = 0.f;
#pragma unroll
        for (int k = 0; k < DD; ++k) ch[i][k] = 0.f;
    }

    const int steps = C >> 6;                   // candidates / 64 lanes
    const float4* yq = reinterpret_cast<const float4*>(Y);

    for (int j = 0; j < steps; ++j) {
        const int c = (j << 6) + lane;          // this lane's candidate
        // Y[c][0..15] into registers (coalesced 4KB/wave per step) + bias
        float4 y0 = yq[(size_t)c * 4 + 0];
        float4 y1 = yq[(size_t)c * 4 + 1];
        float4 y2 = yq[(size_t)c * 4 + 2];
        float4 y3 = yq[(size_t)c * 4 + 3];
        float  bv = B[c];
        float yv[DD] = {y0.x,y0.y,y0.z,y0.w, y1.x,y1.y,y1.z,y1.w,
                        y2.x,y2.y,y2.z,y2.w, y3.x,y3.y,y3.z,y3.w};

        float s[SW], arg[SW];
#pragma unroll
        for (int i = 0; i < SW; ++i) {
            float acc = -bv;
#pragma unroll
            for (int k = 0; k < DD; ++k) acc = fmaf(xs[i][k], yv[k], acc);
            s[i]   = acc;                               // score(n_i, c)
            arg[i] = fmaf(acc, T2, -m2[i]);             // exp2 exponent vs lagged max
        }
#pragma unroll
        for (int i = 0; i < SW; ++i) {
            // guarded lagged-max rescale (rare; also fires on first step via m2=-inf -> arg=+inf)
            if (__any(arg[i] > THR)) {
                float smax = wave_max64(s[i]);
                float nm2  = fmaxf(m2[i], smax * T2);
                float sc   = EXP2F(m2[i] - nm2);        // exp2(-inf)=0 handles first step
                l[i]  *= sc;
                fx[i] *= sc;
#pragma unroll
                for (int k = 0; k < DD; ++k) ch[i][k] *= sc;
                m2[i]  = nm2;
                arg[i] = fmaf(s[i], T2, -m2[i]);        // now <= 0 for max lane
            }
            float e = EXP2F(arg[i]);
            l[i] += e;
            fx[i] = fmaf(e, s[i], fx[i]);
#pragma unroll
            for (int k = 0; k < DD; ++k) ch[i][k] = fmaf(e, yv[k], ch[i][k]);
        }
    }

    // cross-lane reductions + normalize + store
#pragma unroll
    for (int i = 0; i < SW; ++i) {
        float lt  = wave_sum64(l[i]);
        float ft  = wave_sum64(fx[i]);
        float inv = 1.0f / lt;
        float cht[DD];
#pragma unroll
        for (int k = 0; k < DD; ++k) cht[k] = wave_sum64(ch[i][k]) * inv;
        if (lane == 0) {
            const int n = nbase + i;
            float4* o = reinterpret_cast<float4*>(out + (size_t)n * DD);
            o[0] = make_float4(cht[0],  cht[1],  cht[2],  cht[3]);
            o[1] = make_float4(cht[4],  cht[5],  cht[6],  cht[7]);
            o[2] = make_float4(cht[8],  cht[9],  cht[10], cht[11]);
            o[3] = make_float4(cht[12], cht[13], cht[14], cht[15]);
            out[(size_t)N * DD + n] = ft * inv;          // f_x
        }
    }
}

extern "C" void kernel_launch(void* const* d_in, const int* in_sizes, int n_in,
                              void* d_out, int out_size, void* d_ws, size_t ws_size,
                              hipStream_t stream) {
    const float* X = (const float*)d_in[0];
    const float* Y = (const float*)d_in[1];   // [1, C, D] contiguous
    const float* B = (const float*)d_in[2];   // [1, C]
    float*     out = (float*)d_out;           // choice [N*D] then f_x [N]

    const int N = in_sizes[0] / DD;           // 32768
    const int C = in_sizes[2];                // 2048 (multiple of 64)

    dim3 grid(N / SW), block(64);
    hipLaunchKernelGGL(finite_fwd, grid, block, 0, stream, X, Y, B, out, N, C);
}